// Round 2
// baseline (678.952 us; speedup 1.0000x reference)
//
#include <hip/hip_runtime.h>
#include <hip/hip_fp16.h>
#include <type_traits>

#define NN 40000
#define EE 640000
#define TT 8
#define RR 16
#define HH 8
#define DIM 128
#define NEG_BIG (-3.402823466e38f)
#define INV_SQRT_OUT 0.08838834764831845f   // 1/sqrt(128); reference divides by sqrt(out_dim)

// ---------------- utility: zero a range of ints (replaces hipMemsetAsync for capture safety) ----------------

__global__ void zero_k(int* __restrict__ p, int n) {
  int i = blockIdx.x * blockDim.x + threadIdx.x;
  if (i < n) p[i] = 0;
}

// ---------------- histogram / scan / scatter (type-sorted node list + dst-CSR + etype-sorted edge list) ----------------

__global__ void hist_nodes_k(const int* __restrict__ ntype, int* __restrict__ cnt_t) {
  __shared__ int lc[TT];
  int tid = threadIdx.x;
  if (tid < TT) lc[tid] = 0;
  __syncthreads();
  int n = blockIdx.x * blockDim.x + tid;
  if (n < NN) atomicAdd(&lc[ntype[n]], 1);
  __syncthreads();
  if (tid < TT && lc[tid]) atomicAdd(&cnt_t[tid], lc[tid]);
}

__global__ void hist_edges_k(const int* __restrict__ dst, const int* __restrict__ etype,
                             int* __restrict__ deg, int* __restrict__ cnt_r) {
  __shared__ int lc[RR];
  int tid = threadIdx.x;
  if (tid < RR) lc[tid] = 0;
  __syncthreads();
  int e = blockIdx.x * blockDim.x + tid;
  if (e < EE) {
    atomicAdd(&deg[dst[e]], 1);
    atomicAdd(&lc[etype[e]], 1);
  }
  __syncthreads();
  if (tid < RR && lc[tid]) atomicAdd(&cnt_r[tid], lc[tid]);
}

__global__ __launch_bounds__(1024) void scan_k(
    const int* __restrict__ cnt_t, int* __restrict__ toff, int* __restrict__ tcur,
    const int* __restrict__ cnt_r, int* __restrict__ roff, int* __restrict__ rcur,
    const int* __restrict__ deg, int* __restrict__ off, int* __restrict__ cur) {
  __shared__ int tot[1024];
  int tid = threadIdx.x;
  if (tid == 0) {
    int a = 0;
    for (int t = 0; t < TT; ++t) { toff[t] = a; tcur[t] = a; a += cnt_t[t]; }
    toff[TT] = a;
    a = 0;
    for (int r = 0; r < RR; ++r) { roff[r] = a; rcur[r] = a; a += cnt_r[r]; }
    roff[RR] = a;
  }
  const int NPT = (NN + 1023) / 1024;  // 40
  int base = tid * NPT;
  int s = 0;
  for (int k = 0; k < NPT; ++k) { int i = base + k; if (i < NN) s += deg[i]; }
  tot[tid] = s;
  __syncthreads();
  for (int st = 1; st < 1024; st <<= 1) {
    int v = (tid >= st) ? tot[tid - st] : 0;
    __syncthreads();
    tot[tid] += v;
    __syncthreads();
  }
  int run = (tid > 0) ? tot[tid - 1] : 0;  // exclusive prefix of this chunk
  for (int k = 0; k < NPT; ++k) {
    int i = base + k;
    if (i < NN) {
      cur[i] = run;          // start cursor for node i (== off[i])
      run += deg[i];
      off[i + 1] = run;
    }
  }
  if (tid == 0) off[0] = 0;
}

__global__ void scatter_nodes_k(const int* __restrict__ ntype, int* __restrict__ tcur,
                                int* __restrict__ perm) {
  __shared__ int lc[TT], lb[TT];
  int tid = threadIdx.x;
  if (tid < TT) lc[tid] = 0;
  __syncthreads();
  int n = blockIdx.x * blockDim.x + tid;
  int t = 0, rank = 0;
  bool valid = (n < NN);
  if (valid) { t = ntype[n]; rank = atomicAdd(&lc[t], 1); }
  __syncthreads();
  if (tid < TT && lc[tid]) lb[tid] = atomicAdd(&tcur[tid], lc[tid]);
  __syncthreads();
  if (valid) perm[lb[t] + rank] = n;
}

__global__ void scatter_edges_k(const int* __restrict__ dst, const int* __restrict__ etype,
                                int* __restrict__ cur, int* __restrict__ rcur,
                                int* __restrict__ eid_dst, int* __restrict__ eid_r) {
  __shared__ int lc[RR], lb[RR];
  int tid = threadIdx.x;
  if (tid < RR) lc[tid] = 0;
  __syncthreads();
  int e = blockIdx.x * blockDim.x + tid;
  int r = 0, rank = 0;
  bool valid = (e < EE);
  if (valid) {
    int dd = dst[e];
    int p = atomicAdd(&cur[dd], 1);
    eid_dst[p] = e;
    r = etype[e];
    rank = atomicAdd(&lc[r], 1);
  }
  __syncthreads();
  if (tid < RR && lc[tid]) lb[tid] = atomicAdd(&rcur[tid], lc[tid]);
  __syncthreads();
  if (valid) eid_r[lb[r] + rank] = e;
}

// ---------------- type-indexed projection: blocks of 64 same-type nodes, weights reused x16 in registers ----------------

template <int NMAT, bool GATE>
__global__ __launch_bounds__(256) void proj_k(
    const float* __restrict__ X,
    const float* __restrict__ W0, const float* __restrict__ W1, const float* __restrict__ W2,
    float* O0, float* O1, float* O2,
    const int* __restrict__ perm, const int* __restrict__ toff,
    const float* __restrict__ skipw) {
  __shared__ float xs[64 * DIM];
  __shared__ int pid[64];
  int t = blockIdx.y;
  int b0 = toff[t] + blockIdx.x * 64;
  int bn = toff[t + 1] - b0;
  if (bn <= 0) return;
  if (bn > 64) bn = 64;
  int tid = threadIdx.x;
  if (tid < 64) pid[tid] = perm[b0 + ((tid < bn) ? tid : 0)];  // pad with first node (benign dup writes)
  __syncthreads();
  for (int s = tid; s < 64 * 32; s += 256) {
    int row = s >> 5, c4 = s & 31;
    *(float4*)&xs[row * DIM + c4 * 4] = *(const float4*)&X[(size_t)pid[row] * DIM + c4 * 4];
  }
  __syncthreads();
  int p = tid & 63, q = tid >> 6;
  int oc = 2 * p;
  float gate = 1.f;
  if (GATE) {
    float sk = skipw[t * HH + (oc >> 4)];
    gate = 1.f / (1.f + __expf(-sk));
  }
  const float* Ws[3] = {W0, W1, W2};
  float* Os[3] = {O0, O1, O2};
#pragma unroll
  for (int mat = 0; mat < NMAT; ++mat) {
    const float* W = Ws[mat] + (size_t)t * DIM * DIM;
    float acc0[16], acc1[16];
#pragma unroll
    for (int m = 0; m < 16; ++m) { acc0[m] = 0.f; acc1[m] = 0.f; }
    for (int i4 = 0; i4 < 32; ++i4) {
      int i = i4 * 4;
      float2 w0 = *(const float2*)&W[(i + 0) * DIM + oc];
      float2 w1 = *(const float2*)&W[(i + 1) * DIM + oc];
      float2 w2 = *(const float2*)&W[(i + 2) * DIM + oc];
      float2 w3 = *(const float2*)&W[(i + 3) * DIM + oc];
#pragma unroll
      for (int m = 0; m < 16; ++m) {
        float4 xv = *(const float4*)&xs[(q * 16 + m) * DIM + i];
        acc0[m] += xv.x * w0.x + xv.y * w1.x + xv.z * w2.x + xv.w * w3.x;
        acc1[m] += xv.x * w0.y + xv.y * w1.y + xv.z * w2.y + xv.w * w3.y;
      }
    }
    float* O = Os[mat];
#pragma unroll
    for (int m = 0; m < 16; ++m) {
      float2 val = {acc0[m] * gate, acc1[m] * gate};
      *(float2*)&O[(size_t)pid[q * 16 + m] * DIM + oc] = val;
    }
  }
}

// ---------------- per-edge relation transform (etype-sorted; relation pair staged in LDS, XOR-swizzled) ----------------

template <typename VT, bool WV2>
__global__ __launch_bounds__(256) void edge_k(
    const float* __restrict__ kn, const float* __restrict__ qn, const float* __restrict__ vn,
    const float* __restrict__ attw, const float* __restrict__ msgw, const float* __restrict__ pri,
    const int* __restrict__ src, const int* __restrict__ dst,
    const int* __restrict__ roff, const int* __restrict__ eidr,
    float* __restrict__ attn_ws, VT* __restrict__ v2) {
  int r = blockIdx.y;
  int base = roff[r];
  int cnt = roff[r + 1] - base;
  int tile0 = blockIdx.x * 256;
  if (tile0 >= cnt) return;
  __shared__ float att_sw[2048];
  __shared__ float msg_sw[2048];
  __shared__ int eid[256];
  int tid = threadIdx.x;
  {
    const float* A = attw + (size_t)r * 2048;
    const float* M = msgw + (size_t)r * 2048;
    for (int idx = tid; idx < 2048; idx += 256) {
      int hh = idx >> 8, dd = (idx >> 4) & 15, cc = idx & 15;
      // swizzled [h][c][d-quad] layout: 16B unit u = h*64+c*4+(d>>2), XOR h -> spread across bank groups
      int u = ((((hh << 6) + (cc << 2) + (dd >> 2)) ^ hh) << 2) + (dd & 3);
      att_sw[u] = A[idx];
      if (WV2) msg_sw[u] = M[idx];
    }
  }
  eid[tid] = (tile0 + tid < cnt) ? eidr[base + tile0 + tid] : -1;
  __syncthreads();
  int h = tid & 7;
  float prih = pri[r * HH + h] * INV_SQRT_OUT;
  for (int pass = 0; pass < 8; ++pass) {
    int e = eid[(pass << 5) + (tid >> 3)];
    if (e < 0) continue;
    int s = src[e], d = dst[e];
    float kk[16], qq[16];
    const float* kp = kn + (size_t)s * DIM + h * 16;
    *(float4*)&kk[0] = *(const float4*)(kp + 0);
    *(float4*)&kk[4] = *(const float4*)(kp + 4);
    *(float4*)&kk[8] = *(const float4*)(kp + 8);
    *(float4*)&kk[12] = *(const float4*)(kp + 12);
    const float* qp = qn + (size_t)d * DIM + h * 16;
    *(float4*)&qq[0] = *(const float4*)(qp + 0);
    *(float4*)&qq[4] = *(const float4*)(qp + 4);
    *(float4*)&qq[8] = *(const float4*)(qp + 8);
    *(float4*)&qq[12] = *(const float4*)(qp + 12);
    float attn = 0.f;
#pragma unroll
    for (int c = 0; c < 16; ++c) {
      float k2c = 0.f;
#pragma unroll
      for (int dq = 0; dq < 4; ++dq) {
        float4 av = *(const float4*)&att_sw[((((h << 6) + (c << 2) + dq) ^ h) << 2)];
        k2c += kk[dq * 4 + 0] * av.x + kk[dq * 4 + 1] * av.y + kk[dq * 4 + 2] * av.z + kk[dq * 4 + 3] * av.w;
      }
      attn += k2c * qq[c];
    }
    attn_ws[(size_t)e * HH + h] = attn * prih;
    if constexpr (WV2) {
      float vv[16], o16[16];
      const float* vp = vn + (size_t)s * DIM + h * 16;
      *(float4*)&vv[0] = *(const float4*)(vp + 0);
      *(float4*)&vv[4] = *(const float4*)(vp + 4);
      *(float4*)&vv[8] = *(const float4*)(vp + 8);
      *(float4*)&vv[12] = *(const float4*)(vp + 12);
#pragma unroll
      for (int c = 0; c < 16; ++c) {
        float vc = 0.f;
#pragma unroll
        for (int dq = 0; dq < 4; ++dq) {
          float4 mv = *(const float4*)&msg_sw[((((h << 6) + (c << 2) + dq) ^ h) << 2)];
          vc += vv[dq * 4 + 0] * mv.x + vv[dq * 4 + 1] * mv.y + vv[dq * 4 + 2] * mv.z + vv[dq * 4 + 3] * mv.w;
        }
        o16[c] = vc;
      }
      VT* vo = v2 + (size_t)e * DIM + h * 16;
      if constexpr (std::is_same<VT, float>::value) {
        *(float4*)(vo + 0) = make_float4(o16[0], o16[1], o16[2], o16[3]);
        *(float4*)(vo + 4) = make_float4(o16[4], o16[5], o16[6], o16[7]);
        *(float4*)(vo + 8) = make_float4(o16[8], o16[9], o16[10], o16[11]);
        *(float4*)(vo + 12) = make_float4(o16[12], o16[13], o16[14], o16[15]);
      } else {
        __half2* vo2 = (__half2*)vo;
#pragma unroll
        for (int i = 0; i < 8; ++i) vo2[i] = __floats2half2_rn(o16[2 * i], o16[2 * i + 1]);
      }
    }
  }
}

// ---------------- dst-centric exact segment softmax + message reduce (wave per node, no atomics) ----------------

__device__ __forceinline__ float ldv2(const float* p) { return *p; }
__device__ __forceinline__ float ldv2(const __half* p) { return __half2float(*p); }

// Pass A shared by both node kernels: per-head (max, sum-exp) online reduce.
__device__ __forceinline__ void softmax_stats(
    const int* __restrict__ eid_dst, const float* __restrict__ attn_ws,
    int beg, int end, int lane, float& MA, float& rA, float& MB, float& rB) {
  int j = lane >> 3, hh = lane & 7;
  float m = NEG_BIG, ssum = 0.f;
  for (int b = beg + j; b < end; b += 8) {
    int e = eid_dst[b];
    float a = attn_ws[(size_t)e * HH + hh];
    if (a > m) { ssum = ssum * __expf(m - a) + 1.f; m = a; }
    else ssum += __expf(a - m);
  }
#pragma unroll
  for (int mk = 8; mk <= 32; mk <<= 1) {
    float mo = __shfl_xor(m, mk);
    float so = __shfl_xor(ssum, mk);
    float M = fmaxf(m, mo);
    ssum = ssum * __expf(m - M) + so * __expf(mo - M);
    m = M;
  }
  int hA = lane >> 4, hB = hA + 4;
  MA = __shfl(m, hA);
  float SA = __shfl(ssum, hA);
  MB = __shfl(m, hB);
  float SB = __shfl(ssum, hB);
  rA = 1.f / SA;
  rB = 1.f / SB;
}

template <typename VT>
__global__ __launch_bounds__(256) void node_k(
    const int* __restrict__ off, const int* __restrict__ eid_dst,
    const float* __restrict__ attn_ws, const VT* __restrict__ v2,
    float* __restrict__ tbuf) {
  int wid = threadIdx.x >> 6, lane = threadIdx.x & 63;
  int n = blockIdx.x * 4 + wid;
  if (n >= NN) return;
  int beg = off[n], end = off[n + 1];
  float t0 = 0.f, t1 = 0.f;
  if (end > beg) {
    float MA, rA, MB, rB;
    softmax_stats(eid_dst, attn_ws, beg, end, lane, MA, rA, MB, rB);
    int hA = lane >> 4, hB = hA + 4;
    for (int b = beg; b < end; ++b) {
      int e = eid_dst[b];
      float aA = attn_ws[(size_t)e * HH + hA];
      float aB = attn_ws[(size_t)e * HH + hB];
      float wA = __expf(aA - MA) * rA;
      float wB = __expf(aB - MB) * rB;
      t0 += wA * ldv2(&v2[(size_t)e * DIM + lane]);
      t1 += wB * ldv2(&v2[(size_t)e * DIM + 64 + lane]);
    }
  }
  tbuf[(size_t)n * DIM + lane] = t0;
  tbuf[(size_t)n * DIM + 64 + lane] = t1;
}

// Tier-3: recompute v2 per edge from global relation_msg (131 KB total, L1/L2-resident).
__global__ __launch_bounds__(256) void node_rec_k(
    const int* __restrict__ off, const int* __restrict__ eid_dst,
    const float* __restrict__ attn_ws, const float* __restrict__ vn,
    const int* __restrict__ src, const int* __restrict__ etype,
    const float* __restrict__ msgw, float* __restrict__ tbuf) {
  int wid = threadIdx.x >> 6, lane = threadIdx.x & 63;
  int n = blockIdx.x * 4 + wid;
  if (n >= NN) return;
  int beg = off[n], end = off[n + 1];
  float t0 = 0.f, t1 = 0.f;
  if (end > beg) {
    float MA, rA, MB, rB;
    softmax_stats(eid_dst, attn_ws, beg, end, lane, MA, rA, MB, rB);
    int hA = lane >> 4, hB = hA + 4, c = lane & 15;
    for (int b = beg; b < end; ++b) {
      int e = eid_dst[b];
      int s = src[e], r = etype[e];
      float wA = __expf(attn_ws[(size_t)e * HH + hA] - MA) * rA;
      float wB = __expf(attn_ws[(size_t)e * HH + hB] - MB) * rB;
      const float* vpA = vn + (size_t)s * DIM + hA * 16;
      const float* vpB = vn + (size_t)s * DIM + hB * 16;
      const float* mpA = msgw + (size_t)r * 2048 + hA * 256 + c;
      const float* mpB = msgw + (size_t)r * 2048 + hB * 256 + c;
      float v2A = 0.f, v2B = 0.f;
#pragma unroll
      for (int d = 0; d < 16; ++d) {
        v2A += vpA[d] * mpA[d * 16];
        v2B += vpB[d] * mpB[d * 16];
      }
      t0 += wA * v2A;
      t1 += wB * v2B;
    }
  }
  tbuf[(size_t)n * DIM + lane] = t0;
  tbuf[(size_t)n * DIM + 64 + lane] = t1;
}

// ---------------- launch ----------------

extern "C" void kernel_launch(void* const* d_in, const int* in_sizes, int n_in,
                              void* d_out, int out_size, void* d_ws, size_t ws_size,
                              hipStream_t stream) {
  const float* h_in = (const float*)d_in[0];
  const float* k_w = (const float*)d_in[1];
  const float* q_w = (const float*)d_in[2];
  const float* v_w = (const float*)d_in[3];
  const float* a_w = (const float*)d_in[4];
  const float* pri = (const float*)d_in[5];
  const float* att = (const float*)d_in[6];
  const float* msgw = (const float*)d_in[7];
  const float* skipw = (const float*)d_in[8];
  const int* src = (const int*)d_in[9];
  const int* dst = (const int*)d_in[10];
  const int* ntype = (const int*)d_in[11];
  const int* etype = (const int*)d_in[12];
  float* out = (float*)d_out;

  char* w = (char*)d_ws;
  size_t o = 0;
  auto take = [&](size_t bytes) -> char* {
    char* p = w + o;
    o += (bytes + 255) & ~(size_t)255;
    return p;
  };
  float* kn = (float*)take((size_t)NN * DIM * 4);   // aliased by tbuf after edge_k
  float* qn = (float*)take((size_t)NN * DIM * 4);
  float* vn = (float*)take((size_t)NN * DIM * 4);
  float* attn_ws = (float*)take((size_t)EE * HH * 4);
  int* small = (int*)take(1024);
  int* deg = (int*)take((size_t)NN * 4);
  int* off = (int*)take((size_t)(NN + 1) * 4);
  int* cur = (int*)take((size_t)(NN + 1) * 4);
  int* perm = (int*)take((size_t)NN * 4);
  int* eidd = (int*)take((size_t)EE * 4);
  int* eidr = (int*)take((size_t)EE * 4);
  size_t fixed_end = o;
  float* tb = kn;  // kn dead after edge_k; node kernels write tb, final proj reads tb

  int* cnt_t = small;       // 8
  int* toff = small + 8;    // 9
  int* tcur = small + 17;   // 8
  int* cnt_r = small + 25;  // 16
  int* roff = small + 41;   // 17
  int* rcur = small + 58;   // 16

  // zero counters (small, 256 ints) + deg (NN ints); contiguous by construction
  zero_k<<<(256 + NN + 255) / 256, 256, 0, stream>>>(small, 256 + NN);

  hist_nodes_k<<<(NN + 255) / 256, 256, 0, stream>>>(ntype, cnt_t);
  hist_edges_k<<<(EE + 255) / 256, 256, 0, stream>>>(dst, etype, deg, cnt_r);
  scan_k<<<1, 1024, 0, stream>>>(cnt_t, toff, tcur, cnt_r, roff, rcur, deg, off, cur);
  scatter_nodes_k<<<(NN + 255) / 256, 256, 0, stream>>>(ntype, tcur, perm);
  scatter_edges_k<<<(EE + 255) / 256, 256, 0, stream>>>(dst, etype, cur, rcur, eidd, eidr);

  proj_k<3, false><<<dim3(112, TT), 256, 0, stream>>>(h_in, k_w, q_w, v_w, kn, qn, vn, perm, toff, nullptr);

  size_t need32 = fixed_end + (size_t)EE * DIM * 4;
  size_t need16 = fixed_end + (size_t)EE * DIM * 2;
  if (ws_size >= need32) {
    float* v2 = (float*)(w + fixed_end);
    edge_k<float, true><<<dim3(176, RR), 256, 0, stream>>>(kn, qn, vn, att, msgw, pri, src, dst, roff, eidr, attn_ws, v2);
    node_k<float><<<(NN + 3) / 4, 256, 0, stream>>>(off, eidd, attn_ws, v2, tb);
  } else if (ws_size >= need16) {
    __half* v2 = (__half*)(w + fixed_end);
    edge_k<__half, true><<<dim3(176, RR), 256, 0, stream>>>(kn, qn, vn, att, msgw, pri, src, dst, roff, eidr, attn_ws, v2);
    node_k<__half><<<(NN + 3) / 4, 256, 0, stream>>>(off, eidd, attn_ws, v2, tb);
  } else {
    edge_k<float, false><<<dim3(176, RR), 256, 0, stream>>>(kn, qn, vn, att, msgw, pri, src, dst, roff, eidr, attn_ws, (float*)nullptr);
    node_rec_k<<<(NN + 3) / 4, 256, 0, stream>>>(off, eidd, attn_ws, vn, src, etype, msgw, tb);
  }

  proj_k<1, true><<<dim3(112, TT), 256, 0, stream>>>(tb, a_w, a_w, a_w, out, out, out, perm, toff, skipw);
}